// Round 12
// baseline (200.240 us; speedup 1.0000x reference)
//
#include <hip/hip_runtime.h>
#include <hip/hip_bf16.h>
#include <cstdint>

#define DIM   1024
#define KEY   128
#define UV    1024
#define NCOL  (UV*2 + KEY)   // 2176
#define SEQ   2048
#define BATCH 4
#define MTOT  (BATCH*SEQ)    // 8192
#define SCALE 0.08838834764831845f  // 1/sqrt(128)

typedef __attribute__((ext_vector_type(8))) short short8;
typedef __attribute__((ext_vector_type(4))) float f32x4;

__device__ inline unsigned short f2b(float x) {
  unsigned int u = __float_as_uint(x);
  unsigned int r = (u + 0x7fffu + ((u >> 16) & 1u)) >> 16;
  return (unsigned short)r;
}
__device__ inline float b2f(unsigned short x) {
  return __uint_as_float(((unsigned int)x) << 16);
}

__device__ inline void gload_lds16(const void* g, void* l) {
  __builtin_amdgcn_global_load_lds(
      (const __attribute__((address_space(1))) unsigned int*)g,
      (__attribute__((address_space(3))) unsigned int*)l, 16, 0, 0);
}

// ---------------------------------------------------------------------------
// 128x128 bt-GEMM tile, 4 waves (2x2), wave-tile 64x64, BK=32, double-buffered
// with counted vmcnt(4).  (round-6 core — UNCHANGED; conflicts 0.)
// r12 change is OUTSIDE: gemm1's LDS shrunk to exactly 32 KiB so it reaches
// 5 blocks/CU -> its 1088-block grid fits ONE residency round (was 4/CU =
// 1024 slots -> 64-block tail ran a 2nd round at 6% utilization, ~half the
// kernel's duration).
// ---------------------------------------------------------------------------
__device__ __forceinline__ void gemm128(
    const unsigned short* __restrict__ A, int lda,
    const unsigned short* __restrict__ Bt, int ldb,
    int K, f32x4 acc[4][4], unsigned short* lds) {
  const int tid  = threadIdx.x;
  const int lane = tid & 63;
  const int wid  = tid >> 6;      // 0..3
  const int wr   = wid >> 1, wc = wid & 1;
  const int fr   = lane & 15;
  const int fq   = lane >> 4;

#pragma unroll
  for (int i = 0; i < 4; ++i)
#pragma unroll
    for (int j = 0; j < 4; ++j) acc[i][j] = (f32x4){0.f, 0.f, 0.f, 0.f};

  auto stage = [&](int k, int d) {
    unsigned short* la = lds + d * 8192;
    unsigned short* lb = la + 4096;
#pragma unroll
    for (int p = 0; p < 2; ++p) {
      int c = p * 256 + tid;          // 0..511: r = c>>2, q = c&3
      int r = c >> 2, q = c & 3;
      int qs = q ^ ((r >> 1) & 3);    // pre-swizzled source
      gload_lds16(A + (size_t)r * lda + k * 32 + qs * 8,
                  la + (size_t)(p * 256 + wid * 64) * 8);
    }
#pragma unroll
    for (int p = 0; p < 2; ++p) {
      int c = p * 256 + tid;
      int r = c >> 2, q = c & 3;
      int qs = q ^ ((r >> 1) & 3);
      gload_lds16(Bt + (size_t)r * ldb + k * 32 + qs * 8,
                  lb + (size_t)(p * 256 + wid * 64) * 8);
    }
  };

  const int slot = (fq ^ ((fr >> 1) & 3)) * 8;
  const int rA   = (wr * 64 + fr) * 32 + slot;   // + i*512
  const int rB   = (wc * 64 + fr) * 32 + slot;   // + j*512

  const int NK = K >> 5;
  stage(0, 0);
  for (int k = 0; k < NK; ++k) {
    const int d = k & 1;
    if (k + 1 < NK) {
      stage(k + 1, d ^ 1);
      asm volatile("s_waitcnt vmcnt(4)" ::: "memory");  // stage(k) landed;
                                                        // stage(k+1) in flight
    } else {
      asm volatile("s_waitcnt vmcnt(0)" ::: "memory");
    }
    __builtin_amdgcn_s_barrier();
    asm volatile("" ::: "memory");
    const unsigned short* la = lds + d * 8192;
    const unsigned short* lb = la + 4096;
    short8 af[4], bf[4];
#pragma unroll
    for (int s = 0; s < 4; ++s) {
      af[s] = *(const short8*)&la[rA + s * 512];
      bf[s] = *(const short8*)&lb[rB + s * 512];
    }
#pragma unroll
    for (int i = 0; i < 4; ++i)
#pragma unroll
      for (int j = 0; j < 4; ++j)
        acc[i][j] = __builtin_amdgcn_mfma_f32_16x16x32_bf16(af[i], bf[j], acc[i][j], 0, 0, 0);
    asm volatile("" ::: "memory");
    __builtin_amdgcn_s_barrier();   // reads of buf d done; next iter may overwrite
    asm volatile("" ::: "memory");
  }
  // After the closing barrier, every wave's LDS reads are complete -> LDS
  // reusable by epilogue.
}

// C/D mapping: row = wr*64 + i*16 + fq*4 + r ; col = wc*64 + j*16 + fr
#define EPILOGUE_COORDS()                      \
  const int lane = threadIdx.x & 63;           \
  const int wid  = threadIdx.x >> 6;           \
  const int wr   = wid >> 1, wc = wid & 1;     \
  const int fr   = lane & 15;                  \
  const int fq   = lane >> 4;

// XCD-aware swizzle over a 2D grid (r10 mapping — measured better than
// natural order (r11): scatters concurrent panel reads across L2 banks)
__device__ __forceinline__ void xcd_swz(int& tx, int& ty) {
  const int gx = gridDim.x, gy = gridDim.y;
  const int n = gx * gy;
  const int D = blockIdx.y * gx + blockIdx.x;
  const int c = (D & 7) * (n >> 3) + (D >> 3);
  tx = c / gy;
  ty = c - tx * gy;
}

// ---------------------------------------------------------------------------
// k_prep: merged {h->bf16 cvt | mask rowsum+bitpack | Wi^T cvt | Wo^T cvt}
// ---------------------------------------------------------------------------
#define PREP_CVT   8192
#define PREP_MASK  2048
#define PREP_TWI   2176   // (NCOL/32) x (DIM/32) = 68 x 32
#define PREP_TWO   1024   // (UV/32)  x (DIM/32) = 32 x 32

__global__ __launch_bounds__(256) void k_prep(
    const float* __restrict__ h, unsigned short* __restrict__ hbf,
    const int* __restrict__ mask, float* __restrict__ ll, unsigned int* __restrict__ mb,
    const float* __restrict__ Wi, unsigned short* __restrict__ WiT,
    const float* __restrict__ Wo, unsigned short* __restrict__ WoT) {
  __shared__ float t[32][33];
  const int bid = blockIdx.x;
  const int tid = threadIdx.x;

  if (bid < PREP_CVT) {
    int id = bid * 256 + tid;
    float4 f = ((const float4*)h)[id];
    ushort4 o;
    o.x = f2b(f.x); o.y = f2b(f.y); o.z = f2b(f.z); o.w = f2b(f.w);
    ((ushort4*)hbf)[id] = o;
  } else if (bid < PREP_CVT + PREP_MASK) {
    int wid = tid >> 6, lane = tid & 63;
    int row = (bid - PREP_CVT) * 4 + wid;
    const int4* p = (const int4*)(mask + (size_t)row * SEQ);
    int s = 0;
#pragma unroll
    for (int i = 0; i < 8; ++i) {
      int4 v = p[i * 64 + lane];
      unsigned nib = (v.x != 0 ? 1u : 0u) | (v.y != 0 ? 2u : 0u) |
                     (v.z != 0 ? 4u : 0u) | (v.w != 0 ? 8u : 0u);
      unsigned w = 0;
#pragma unroll
      for (int k2 = 0; k2 < 8; ++k2)
        w |= __shfl(nib, (lane & ~7) + k2, 64) << (4 * k2);
      if ((lane & 7) == 0) mb[(size_t)row * 64 + i * 8 + (lane >> 3)] = w;
      s += v.x + v.y + v.z + v.w;
    }
    for (int off = 32; off; off >>= 1) s += __shfl_down(s, off);
    if (lane == 0) ll[row] = (float)s;
  } else {
    const float* in; unsigned short* outp; int R, C, bx, by;
    if (bid < PREP_CVT + PREP_MASK + PREP_TWI) {
      int b = bid - (PREP_CVT + PREP_MASK);
      in = Wi; outp = WiT; R = DIM; C = NCOL; bx = b % 68; by = b / 68;
    } else {
      int b = bid - (PREP_CVT + PREP_MASK + PREP_TWI);
      in = Wo; outp = WoT; R = DIM; C = UV; bx = b & 31; by = b >> 5;
    }
    int c0 = bx * 32, r0 = by * 32;
    int tx = tid & 31, ty = tid >> 5;   // 32 x 8
#pragma unroll
    for (int i = 0; i < 4; ++i)
      t[ty + i * 8][tx] = in[(size_t)(r0 + ty + i * 8) * C + c0 + tx];
    __syncthreads();
#pragma unroll
    for (int i = 0; i < 4; ++i)
      outp[(size_t)(c0 + ty + i * 8) * R + r0 + tx] = f2b(t[tx][ty + i * 8]);
  }
}

// ---------------------------------------------------------------------------
// GEMM kernels (128x128 tiles, 256 threads, 32 KiB static LDS)
// gemm1: 5 blocks/CU (1088 blocks -> single residency round)
// ---------------------------------------------------------------------------
__global__ __launch_bounds__(256, 5) void k_gemm1(const unsigned short* __restrict__ hbf,
                                                  const unsigned short* __restrict__ WiT,
                                                  const float* __restrict__ bi,
                                                  const float* __restrict__ sn,
                                                  const float* __restrict__ cs,
                                                  const float* __restrict__ qg,
                                                  const float* __restrict__ qb,
                                                  const float* __restrict__ kg,
                                                  const float* __restrict__ kb,
                                                  unsigned short* __restrict__ u,
                                                  unsigned short* __restrict__ vT,
                                                  unsigned short* __restrict__ qbuf,
                                                  unsigned short* __restrict__ kbuf) {
  // exactly 32 KiB: GEMM double-buffer; reused (group-XOR swizzled, no pad)
  // as the v-transpose staging buffer after the GEMM's closing barrier.
  __shared__ unsigned short lds[16384];
  int tx, ty; xcd_swz(tx, ty);
  int m0 = tx * 128, n0 = ty * 128;
  f32x4 acc[4][4];
  gemm128(hbf + (size_t)m0 * DIM, DIM, WiT + (size_t)n0 * DIM, DIM, DIM, acc, lds);
  EPILOGUE_COORDS();
  if (n0 < UV) {
    // u columns: silu + pack
#pragma unroll
    for (int i = 0; i < 4; ++i)
#pragma unroll
      for (int j = 0; j < 4; ++j)
#pragma unroll
        for (int r = 0; r < 4; ++r) {
          int row = m0 + wr * 64 + i * 16 + fq * 4 + r;
          int col = n0 + wc * 64 + j * 16 + fr;
          float x = acc[i][j][r] + bi[col];
          float s = x / (1.f + __expf(-x));
          u[(size_t)row * UV + col] = f2b(s);
        }
  } else if (n0 < 2 * UV) {
    // v columns: silu + in-block transpose -> write vT[b][d][n] directly.
    // 32 KiB layout: logical t[dl][rl] stored at elem dl*128 + (rl ^ ((dl&7)<<3))
    // (group-XOR: 8-elem groups permuted per row; u32 writes aligned, 16B
    // reads contiguous at group q^(dl&7); <=2-way banks both sides).
#pragma unroll
    for (int i = 0; i < 4; ++i)
#pragma unroll
      for (int j = 0; j < 4; ++j)
#pragma unroll
        for (int r = 0; r < 4; r += 2) {
          int rl = wr * 64 + i * 16 + fq * 4 + r;     // local row (even)
          int dl = wc * 64 + j * 16 + fr;             // local v-col
          int col = n0 + dl;
          float x0 = acc[i][j][r]     + bi[col];
          float x1 = acc[i][j][r + 1] + bi[col];
          float s0 = x0 / (1.f + __expf(-x0));
          float s1 = x1 / (1.f + __expf(-x1));
          unsigned pk = (unsigned)f2b(s0) | ((unsigned)f2b(s1) << 16);
          *(unsigned*)&lds[dl * 128 + (rl ^ ((dl & 7) << 3))] = pk;
        }
    __syncthreads();
    int bb = m0 >> 11;            // batch  (SEQ = 2048)
    int ns = m0 & (SEQ - 1);      // seq base
    int d0 = n0 - UV;
    const int tid = threadIdx.x;
#pragma unroll
    for (int it = 0; it < 8; ++it) {
      int idx = it * 256 + tid;   // 0..2047
      int dl = idx >> 4, q = idx & 15;
      *(int4*)&vT[((size_t)bb * UV + d0 + dl) * SEQ + ns + q * 8] =
          *(const int4*)&lds[dl * 128 + ((q ^ (dl & 7)) << 3)];
    }
  } else {
    // KEY columns: silu + gamma/beta + rotary, write qbuf/kbuf bf16.
    const int colk_base = wc * 64;
    const bool ev = (fr & 1) == 0;
#pragma unroll
    for (int i = 0; i < 4; ++i)
#pragma unroll
      for (int j = 0; j < 4; ++j)
#pragma unroll
        for (int r = 0; r < 4; ++r) {
          int row  = m0 + wr * 64 + i * 16 + fq * 4 + r;
          int colk = colk_base + j * 16 + fr;           // 0..127
          float x = acc[i][j][r] + bi[2 * UV + colk];
          float s = x / (1.f + __expf(-x));
          float aq = s * qg[colk] + qb[colk];
          float ak = s * kg[colk] + kb[colk];
          float aqx = __shfl_xor(aq, 1);
          float akx = __shfl_xor(ak, 1);
          int t_ = colk >> 1;
          int n  = row & (SEQ - 1);
          float cc = cs[n * 64 + t_], ss = sn[n * 64 + t_];
          float q1 = ev ? aq : aqx, q2 = ev ? aqx : aq;
          float k1 = ev ? ak : akx, k2 = ev ? akx : ak;
          float resq = ev ? (q1 * cc - q2 * ss) : (q1 * ss + q2 * cc);
          float resk = ev ? (k1 * cc - k2 * ss) : (k1 * ss + k2 * cc);
          int oc = ev ? t_ : (64 + t_);
          qbuf[(size_t)row * KEY + oc] = f2b(resq);
          kbuf[(size_t)row * KEY + oc] = f2b(resk);
        }
  }
}

__global__ __launch_bounds__(256, 4) void k_qk(const unsigned short* __restrict__ q,
                                               const unsigned short* __restrict__ k,
                                               const unsigned int* __restrict__ mb,
                                               const float* __restrict__ ll,
                                               unsigned short* __restrict__ Abuf) {
  __shared__ unsigned short lds[16384];
  int b = blockIdx.z;
  int tx, ty; xcd_swz(tx, ty);
  int m0 = tx * 128, n0 = ty * 128;
  f32x4 acc[4][4];
  gemm128(q + ((size_t)b * SEQ + m0) * KEY, KEY,
          k + ((size_t)b * SEQ + n0) * KEY, KEY, KEY, acc, lds);
  EPILOGUE_COORDS();
#pragma unroll
  for (int i = 0; i < 4; ++i)
#pragma unroll
    for (int r = 0; r < 4; ++r) {
      int row = m0 + wr * 64 + i * 16 + fq * 4 + r;
      size_t rb = (size_t)b * SEQ + row;
      unsigned long long mw =
          *(const unsigned long long*)&mb[rb * 64 + (n0 >> 5) + wc * 2];
      float rll = 1.0f / ll[rb];
#pragma unroll
      for (int j = 0; j < 4; ++j) {
        int col = n0 + wc * 64 + j * 16 + fr;
        float a = acc[i][j][r] * SCALE;
        bool on = (mw >> (j * 16 + fr)) & 1ull;
        float rel = (on && a > 0.f) ? a : 0.f;
        Abuf[rb * SEQ + col] = f2b(rel * rel * rll);
      }
    }
}

__global__ __launch_bounds__(256, 4) void k_av(const unsigned short* __restrict__ Abuf,
                                               const unsigned short* __restrict__ vT,
                                               const unsigned short* __restrict__ u,
                                               unsigned short* __restrict__ g) {
  __shared__ unsigned short lds[16384];
  int b = blockIdx.z;
  int tx, ty; xcd_swz(tx, ty);
  int m0 = tx * 128, n0 = ty * 128;
  f32x4 acc[4][4];
  gemm128(Abuf + ((size_t)b * SEQ + m0) * SEQ, SEQ,
          vT + ((size_t)b * UV + n0) * SEQ, SEQ, SEQ, acc, lds);
  EPILOGUE_COORDS();
#pragma unroll
  for (int i = 0; i < 4; ++i)
#pragma unroll
    for (int j = 0; j < 4; ++j)
#pragma unroll
      for (int r = 0; r < 4; ++r) {
        int row = m0 + wr * 64 + i * 16 + fq * 4 + r;
        int col = n0 + wc * 64 + j * 16 + fr;
        size_t gi = ((size_t)b * SEQ + row) * UV + col;
        g[gi] = f2b(acc[i][j][r] * b2f(u[gi]));
      }
}

__global__ __launch_bounds__(256, 4) void k_out(const unsigned short* __restrict__ g,
                                                const unsigned short* __restrict__ WoT,
                                                const float* __restrict__ bo,
                                                float* __restrict__ out) {
  __shared__ unsigned short lds[16384];
  int tx, ty; xcd_swz(tx, ty);
  int m0 = tx * 128, n0 = ty * 128;
  f32x4 acc[4][4];
  gemm128(g + (size_t)m0 * UV, UV, WoT + (size_t)n0 * UV, UV, UV, acc, lds);
  EPILOGUE_COORDS();
#pragma unroll
  for (int i = 0; i < 4; ++i)
#pragma unroll
    for (int j = 0; j < 4; ++j)
#pragma unroll
      for (int r = 0; r < 4; ++r) {
        int row = m0 + wr * 64 + i * 16 + fq * 4 + r;
        int col = n0 + wc * 64 + j * 16 + fr;
        out[(size_t)row * DIM + col] = acc[i][j][r] + bo[col];
      }
}

// ---------------------------------------------------------------------------
extern "C" void kernel_launch(void* const* d_in, const int* in_sizes, int n_in,
                              void* d_out, int out_size, void* d_ws, size_t ws_size,
                              hipStream_t stream) {
  const float* h    = (const float*)d_in[0];
  const int*   mask = (const int*)d_in[1];
  const float* sn   = (const float*)d_in[2];
  const float* cs   = (const float*)d_in[3];
  const float* Wi   = (const float*)d_in[4];
  const float* bi   = (const float*)d_in[5];
  const float* Wo   = (const float*)d_in[6];
  const float* bo   = (const float*)d_in[7];
  const float* qg   = (const float*)d_in[8];
  const float* qb   = (const float*)d_in[9];
  const float* kg   = (const float*)d_in[10];
  const float* kb   = (const float*)d_in[11];
  float* out = (float*)d_out;

  char* ws = (char*)d_ws;
  size_t off = 0;
  auto alloc = [&](size_t bytes) { void* p = ws + off; off += (bytes + 255) & ~(size_t)255; return p; };
  unsigned short* hbf  = (unsigned short*)alloc((size_t)MTOT * DIM * 2);
  unsigned short* WiT  = (unsigned short*)alloc((size_t)NCOL * DIM * 2);
  unsigned short* WoT  = (unsigned short*)alloc((size_t)DIM * UV * 2);
  unsigned short* u    = (unsigned short*)alloc((size_t)MTOT * UV * 2);
  unsigned short* vT   = (unsigned short*)alloc((size_t)MTOT * UV * 2);
  unsigned short* qbuf = (unsigned short*)alloc((size_t)MTOT * KEY * 2);
  unsigned short* kbuf = (unsigned short*)alloc((size_t)MTOT * KEY * 2);
  float*          ll   = (float*)alloc((size_t)MTOT * 4);
  unsigned int*   mbits= (unsigned int*)alloc((size_t)MTOT * 64 * 4);
  unsigned short* Abuf = (unsigned short*)alloc((size_t)BATCH * SEQ * SEQ * 2);
  unsigned short* g    = (unsigned short*)alloc((size_t)MTOT * UV * 2);

  k_prep<<<PREP_CVT + PREP_MASK + PREP_TWI + PREP_TWO, 256, 0, stream>>>(
      h, hbf, mask, ll, mbits, Wi, WiT, Wo, WoT);

  k_gemm1<<<dim3(MTOT / 128, NCOL / 128), 256, 0, stream>>>(
      hbf, WiT, bi, sn, cs, qg, qb, kg, kb, u, vT, qbuf, kbuf);
  k_qk<<<dim3(SEQ / 128, SEQ / 128, BATCH), 256, 0, stream>>>(qbuf, kbuf, mbits, ll, Abuf);
  k_av<<<dim3(SEQ / 128, UV / 128, BATCH), 256, 0, stream>>>(Abuf, vT, u, g);
  k_out<<<dim3(MTOT / 128, DIM / 128), 256, 0, stream>>>(g, WoT, bo, out);
}

// Round 13
// 180.668 us; speedup vs baseline: 1.1083x; 1.1083x over previous
//
#include <hip/hip_runtime.h>
#include <hip/hip_bf16.h>
#include <cstdint>

#define DIM   1024
#define KEY   128
#define UV    1024
#define NCOL  (UV*2 + KEY)   // 2176
#define SEQ   2048
#define BATCH 4
#define MTOT  (BATCH*SEQ)    // 8192
#define SCALE 0.08838834764831845f  // 1/sqrt(128)

typedef __attribute__((ext_vector_type(8))) short short8;
typedef __attribute__((ext_vector_type(4))) float f32x4;

__device__ inline unsigned short f2b(float x) {
  unsigned int u = __float_as_uint(x);
  unsigned int r = (u + 0x7fffu + ((u >> 16) & 1u)) >> 16;
  return (unsigned short)r;
}
__device__ inline float b2f(unsigned short x) {
  return __uint_as_float(((unsigned int)x) << 16);
}

__device__ inline void gload_lds16(const void* g, void* l) {
  __builtin_amdgcn_global_load_lds(
      (const __attribute__((address_space(1))) unsigned int*)g,
      (__attribute__((address_space(3))) unsigned int*)l, 16, 0, 0);
}

// ---------------------------------------------------------------------------
// 128x128 bt-GEMM tile, 4 waves (2x2), wave-tile 64x64, BK=32, double-buffered
// with counted vmcnt(4).  (round-6 core — UNCHANGED; 4 blocks/CU, conflicts 0.
// r12 proved 5 blocks/CU regresses: launch_bounds(256,5) squeezes VGPR 60->48.)
// r13 change is OUTSIDE: XCD swizzle kept ONLY for k_gemm1 (helps its hot
// WiT panels, r10 vs r11: 91 vs 116 µs); k_qk/k_av/k_out use natural order
// (r11 showed they collectively run ~17 µs faster without the swizzle).
// ---------------------------------------------------------------------------
__device__ __forceinline__ void gemm128(
    const unsigned short* __restrict__ A, int lda,
    const unsigned short* __restrict__ Bt, int ldb,
    int K, f32x4 acc[4][4], unsigned short* lds) {
  const int tid  = threadIdx.x;
  const int lane = tid & 63;
  const int wid  = tid >> 6;      // 0..3
  const int wr   = wid >> 1, wc = wid & 1;
  const int fr   = lane & 15;
  const int fq   = lane >> 4;

#pragma unroll
  for (int i = 0; i < 4; ++i)
#pragma unroll
    for (int j = 0; j < 4; ++j) acc[i][j] = (f32x4){0.f, 0.f, 0.f, 0.f};

  auto stage = [&](int k, int d) {
    unsigned short* la = lds + d * 8192;
    unsigned short* lb = la + 4096;
#pragma unroll
    for (int p = 0; p < 2; ++p) {
      int c = p * 256 + tid;          // 0..511: r = c>>2, q = c&3
      int r = c >> 2, q = c & 3;
      int qs = q ^ ((r >> 1) & 3);    // pre-swizzled source
      gload_lds16(A + (size_t)r * lda + k * 32 + qs * 8,
                  la + (size_t)(p * 256 + wid * 64) * 8);
    }
#pragma unroll
    for (int p = 0; p < 2; ++p) {
      int c = p * 256 + tid;
      int r = c >> 2, q = c & 3;
      int qs = q ^ ((r >> 1) & 3);
      gload_lds16(Bt + (size_t)r * ldb + k * 32 + qs * 8,
                  lb + (size_t)(p * 256 + wid * 64) * 8);
    }
  };

  const int slot = (fq ^ ((fr >> 1) & 3)) * 8;
  const int rA   = (wr * 64 + fr) * 32 + slot;   // + i*512
  const int rB   = (wc * 64 + fr) * 32 + slot;   // + j*512

  const int NK = K >> 5;
  stage(0, 0);
  for (int k = 0; k < NK; ++k) {
    const int d = k & 1;
    if (k + 1 < NK) {
      stage(k + 1, d ^ 1);
      asm volatile("s_waitcnt vmcnt(4)" ::: "memory");  // stage(k) landed;
                                                        // stage(k+1) in flight
    } else {
      asm volatile("s_waitcnt vmcnt(0)" ::: "memory");
    }
    __builtin_amdgcn_s_barrier();
    asm volatile("" ::: "memory");
    const unsigned short* la = lds + d * 8192;
    const unsigned short* lb = la + 4096;
    short8 af[4], bf[4];
#pragma unroll
    for (int s = 0; s < 4; ++s) {
      af[s] = *(const short8*)&la[rA + s * 512];
      bf[s] = *(const short8*)&lb[rB + s * 512];
    }
#pragma unroll
    for (int i = 0; i < 4; ++i)
#pragma unroll
      for (int j = 0; j < 4; ++j)
        acc[i][j] = __builtin_amdgcn_mfma_f32_16x16x32_bf16(af[i], bf[j], acc[i][j], 0, 0, 0);
    asm volatile("" ::: "memory");
    __builtin_amdgcn_s_barrier();   // reads of buf d done; next iter may overwrite
    asm volatile("" ::: "memory");
  }
  // After the closing barrier, every wave's LDS reads are complete -> LDS
  // reusable by epilogue.
}

// C/D mapping: row = wr*64 + i*16 + fq*4 + r ; col = wc*64 + j*16 + fr
#define EPILOGUE_COORDS()                      \
  const int lane = threadIdx.x & 63;           \
  const int wid  = threadIdx.x >> 6;           \
  const int wr   = wid >> 1, wc = wid & 1;     \
  const int fr   = lane & 15;                  \
  const int fq   = lane >> 4;

// XCD-aware swizzle over a 2D grid (used by k_gemm1 only — measured win there,
// measured loss on qk/av/out)
__device__ __forceinline__ void xcd_swz(int& tx, int& ty) {
  const int gx = gridDim.x, gy = gridDim.y;
  const int n = gx * gy;
  const int D = blockIdx.y * gx + blockIdx.x;
  const int c = (D & 7) * (n >> 3) + (D >> 3);
  tx = c / gy;
  ty = c - tx * gy;
}

// ---------------------------------------------------------------------------
// k_prep: merged {h->bf16 cvt | mask rowsum+bitpack | Wi^T cvt | Wo^T cvt}
// ---------------------------------------------------------------------------
#define PREP_CVT   8192
#define PREP_MASK  2048
#define PREP_TWI   2176   // (NCOL/32) x (DIM/32) = 68 x 32
#define PREP_TWO   1024   // (UV/32)  x (DIM/32) = 32 x 32

__global__ __launch_bounds__(256) void k_prep(
    const float* __restrict__ h, unsigned short* __restrict__ hbf,
    const int* __restrict__ mask, float* __restrict__ ll, unsigned int* __restrict__ mb,
    const float* __restrict__ Wi, unsigned short* __restrict__ WiT,
    const float* __restrict__ Wo, unsigned short* __restrict__ WoT) {
  __shared__ float t[32][33];
  const int bid = blockIdx.x;
  const int tid = threadIdx.x;

  if (bid < PREP_CVT) {
    int id = bid * 256 + tid;
    float4 f = ((const float4*)h)[id];
    ushort4 o;
    o.x = f2b(f.x); o.y = f2b(f.y); o.z = f2b(f.z); o.w = f2b(f.w);
    ((ushort4*)hbf)[id] = o;
  } else if (bid < PREP_CVT + PREP_MASK) {
    int wid = tid >> 6, lane = tid & 63;
    int row = (bid - PREP_CVT) * 4 + wid;
    const int4* p = (const int4*)(mask + (size_t)row * SEQ);
    int s = 0;
#pragma unroll
    for (int i = 0; i < 8; ++i) {
      int4 v = p[i * 64 + lane];
      unsigned nib = (v.x != 0 ? 1u : 0u) | (v.y != 0 ? 2u : 0u) |
                     (v.z != 0 ? 4u : 0u) | (v.w != 0 ? 8u : 0u);
      unsigned w = 0;
#pragma unroll
      for (int k2 = 0; k2 < 8; ++k2)
        w |= __shfl(nib, (lane & ~7) + k2, 64) << (4 * k2);
      if ((lane & 7) == 0) mb[(size_t)row * 64 + i * 8 + (lane >> 3)] = w;
      s += v.x + v.y + v.z + v.w;
    }
    for (int off = 32; off; off >>= 1) s += __shfl_down(s, off);
    if (lane == 0) ll[row] = (float)s;
  } else {
    const float* in; unsigned short* outp; int R, C, bx, by;
    if (bid < PREP_CVT + PREP_MASK + PREP_TWI) {
      int b = bid - (PREP_CVT + PREP_MASK);
      in = Wi; outp = WiT; R = DIM; C = NCOL; bx = b % 68; by = b / 68;
    } else {
      int b = bid - (PREP_CVT + PREP_MASK + PREP_TWI);
      in = Wo; outp = WoT; R = DIM; C = UV; bx = b & 31; by = b >> 5;
    }
    int c0 = bx * 32, r0 = by * 32;
    int tx = tid & 31, ty = tid >> 5;   // 32 x 8
#pragma unroll
    for (int i = 0; i < 4; ++i)
      t[ty + i * 8][tx] = in[(size_t)(r0 + ty + i * 8) * C + c0 + tx];
    __syncthreads();
#pragma unroll
    for (int i = 0; i < 4; ++i)
      outp[(size_t)(c0 + ty + i * 8) * R + r0 + tx] = f2b(t[tx][ty + i * 8]);
  }
}

// ---------------------------------------------------------------------------
// GEMM kernels (128x128 tiles, 256 threads, static LDS, 4 blocks/CU)
// ---------------------------------------------------------------------------
__global__ __launch_bounds__(256, 4) void k_gemm1(const unsigned short* __restrict__ hbf,
                                                  const unsigned short* __restrict__ WiT,
                                                  const float* __restrict__ bi,
                                                  const float* __restrict__ sn,
                                                  const float* __restrict__ cs,
                                                  const float* __restrict__ qg,
                                                  const float* __restrict__ qb,
                                                  const float* __restrict__ kg,
                                                  const float* __restrict__ kb,
                                                  unsigned short* __restrict__ u,
                                                  unsigned short* __restrict__ vT,
                                                  unsigned short* __restrict__ qbuf,
                                                  unsigned short* __restrict__ kbuf) {
  // 17408 shorts = 34 KiB: first 16384 = GEMM double-buffer; whole array
  // reused as [128][136] transpose pad after the GEMM's closing barrier.
  __shared__ unsigned short lds[17408];
  int tx, ty; xcd_swz(tx, ty);
  int m0 = tx * 128, n0 = ty * 128;
  f32x4 acc[4][4];
  gemm128(hbf + (size_t)m0 * DIM, DIM, WiT + (size_t)n0 * DIM, DIM, DIM, acc, lds);
  EPILOGUE_COORDS();
  if (n0 < UV) {
    // u columns: silu + pack
#pragma unroll
    for (int i = 0; i < 4; ++i)
#pragma unroll
      for (int j = 0; j < 4; ++j)
#pragma unroll
        for (int r = 0; r < 4; ++r) {
          int row = m0 + wr * 64 + i * 16 + fq * 4 + r;
          int col = n0 + wc * 64 + j * 16 + fr;
          float x = acc[i][j][r] + bi[col];
          float s = x / (1.f + __expf(-x));
          u[(size_t)row * UV + col] = f2b(s);
        }
  } else if (n0 < 2 * UV) {
    // v columns: silu + in-block transpose -> write vT[b][d][n] directly
    unsigned short (*t)[136] = (unsigned short (*)[136])lds;
#pragma unroll
    for (int i = 0; i < 4; ++i)
#pragma unroll
      for (int j = 0; j < 4; ++j)
#pragma unroll
        for (int r = 0; r < 4; r += 2) {
          int rl = wr * 64 + i * 16 + fq * 4 + r;     // local row (even)
          int dl = wc * 64 + j * 16 + fr;             // local v-col
          int col = n0 + dl;
          float x0 = acc[i][j][r]     + bi[col];
          float x1 = acc[i][j][r + 1] + bi[col];
          float s0 = x0 / (1.f + __expf(-x0));
          float s1 = x1 / (1.f + __expf(-x1));
          unsigned pk = (unsigned)f2b(s0) | ((unsigned)f2b(s1) << 16);
          *(unsigned*)&t[dl][rl] = pk;
        }
    __syncthreads();
    int bb = m0 >> 11;            // batch  (SEQ = 2048)
    int ns = m0 & (SEQ - 1);      // seq base
    int d0 = n0 - UV;
    const int tid = threadIdx.x;
#pragma unroll
    for (int it = 0; it < 8; ++it) {
      int idx = it * 256 + tid;   // 0..2047
      int dl = idx >> 4, q = idx & 15;
      *(int4*)&vT[((size_t)bb * UV + d0 + dl) * SEQ + ns + q * 8] =
          *(const int4*)&t[dl][q * 8];
    }
  } else {
    // KEY columns: silu + gamma/beta + rotary, write qbuf/kbuf bf16.
    const int colk_base = wc * 64;
    const bool ev = (fr & 1) == 0;
#pragma unroll
    for (int i = 0; i < 4; ++i)
#pragma unroll
      for (int j = 0; j < 4; ++j)
#pragma unroll
        for (int r = 0; r < 4; ++r) {
          int row  = m0 + wr * 64 + i * 16 + fq * 4 + r;
          int colk = colk_base + j * 16 + fr;           // 0..127
          float x = acc[i][j][r] + bi[2 * UV + colk];
          float s = x / (1.f + __expf(-x));
          float aq = s * qg[colk] + qb[colk];
          float ak = s * kg[colk] + kb[colk];
          float aqx = __shfl_xor(aq, 1);
          float akx = __shfl_xor(ak, 1);
          int t_ = colk >> 1;
          int n  = row & (SEQ - 1);
          float cc = cs[n * 64 + t_], ss = sn[n * 64 + t_];
          float q1 = ev ? aq : aqx, q2 = ev ? aqx : aq;
          float k1 = ev ? ak : akx, k2 = ev ? akx : ak;
          float resq = ev ? (q1 * cc - q2 * ss) : (q1 * ss + q2 * cc);
          float resk = ev ? (k1 * cc - k2 * ss) : (k1 * ss + k2 * cc);
          int oc = ev ? t_ : (64 + t_);
          qbuf[(size_t)row * KEY + oc] = f2b(resq);
          kbuf[(size_t)row * KEY + oc] = f2b(resk);
        }
  }
}

__global__ __launch_bounds__(256, 4) void k_qk(const unsigned short* __restrict__ q,
                                               const unsigned short* __restrict__ k,
                                               const unsigned int* __restrict__ mb,
                                               const float* __restrict__ ll,
                                               unsigned short* __restrict__ Abuf) {
  __shared__ unsigned short lds[16384];
  int b = blockIdx.z;
  int m0 = blockIdx.x * 128, n0 = blockIdx.y * 128;   // natural order
  f32x4 acc[4][4];
  gemm128(q + ((size_t)b * SEQ + m0) * KEY, KEY,
          k + ((size_t)b * SEQ + n0) * KEY, KEY, KEY, acc, lds);
  EPILOGUE_COORDS();
#pragma unroll
  for (int i = 0; i < 4; ++i)
#pragma unroll
    for (int r = 0; r < 4; ++r) {
      int row = m0 + wr * 64 + i * 16 + fq * 4 + r;
      size_t rb = (size_t)b * SEQ + row;
      unsigned long long mw =
          *(const unsigned long long*)&mb[rb * 64 + (n0 >> 5) + wc * 2];
      float rll = 1.0f / ll[rb];
#pragma unroll
      for (int j = 0; j < 4; ++j) {
        int col = n0 + wc * 64 + j * 16 + fr;
        float a = acc[i][j][r] * SCALE;
        bool on = (mw >> (j * 16 + fr)) & 1ull;
        float rel = (on && a > 0.f) ? a : 0.f;
        Abuf[rb * SEQ + col] = f2b(rel * rel * rll);
      }
    }
}

__global__ __launch_bounds__(256, 4) void k_av(const unsigned short* __restrict__ Abuf,
                                               const unsigned short* __restrict__ vT,
                                               const unsigned short* __restrict__ u,
                                               unsigned short* __restrict__ g) {
  __shared__ unsigned short lds[16384];
  int b = blockIdx.z;
  int m0 = blockIdx.x * 128, n0 = blockIdx.y * 128;   // natural order
  f32x4 acc[4][4];
  gemm128(Abuf + ((size_t)b * SEQ + m0) * SEQ, SEQ,
          vT + ((size_t)b * UV + n0) * SEQ, SEQ, SEQ, acc, lds);
  EPILOGUE_COORDS();
#pragma unroll
  for (int i = 0; i < 4; ++i)
#pragma unroll
    for (int j = 0; j < 4; ++j)
#pragma unroll
      for (int r = 0; r < 4; ++r) {
        int row = m0 + wr * 64 + i * 16 + fq * 4 + r;
        int col = n0 + wc * 64 + j * 16 + fr;
        size_t gi = ((size_t)b * SEQ + row) * UV + col;
        g[gi] = f2b(acc[i][j][r] * b2f(u[gi]));
      }
}

__global__ __launch_bounds__(256, 4) void k_out(const unsigned short* __restrict__ g,
                                                const unsigned short* __restrict__ WoT,
                                                const float* __restrict__ bo,
                                                float* __restrict__ out) {
  __shared__ unsigned short lds[16384];
  int m0 = blockIdx.x * 128, n0 = blockIdx.y * 128;   // natural order
  f32x4 acc[4][4];
  gemm128(g + (size_t)m0 * UV, UV, WoT + (size_t)n0 * UV, UV, UV, acc, lds);
  EPILOGUE_COORDS();
#pragma unroll
  for (int i = 0; i < 4; ++i)
#pragma unroll
    for (int j = 0; j < 4; ++j)
#pragma unroll
      for (int r = 0; r < 4; ++r) {
        int row = m0 + wr * 64 + i * 16 + fq * 4 + r;
        int col = n0 + wc * 64 + j * 16 + fr;
        out[(size_t)row * DIM + col] = acc[i][j][r] + bo[col];
      }
}

// ---------------------------------------------------------------------------
extern "C" void kernel_launch(void* const* d_in, const int* in_sizes, int n_in,
                              void* d_out, int out_size, void* d_ws, size_t ws_size,
                              hipStream_t stream) {
  const float* h    = (const float*)d_in[0];
  const int*   mask = (const int*)d_in[1];
  const float* sn   = (const float*)d_in[2];
  const float* cs   = (const float*)d_in[3];
  const float* Wi   = (const float*)d_in[4];
  const float* bi   = (const float*)d_in[5];
  const float* Wo   = (const float*)d_in[6];
  const float* bo   = (const float*)d_in[7];
  const float* qg   = (const float*)d_in[8];
  const float* qb   = (const float*)d_in[9];
  const float* kg   = (const float*)d_in[10];
  const float* kb   = (const float*)d_in[11];
  float* out = (float*)d_out;

  char* ws = (char*)d_ws;
  size_t off = 0;
  auto alloc = [&](size_t bytes) { void* p = ws + off; off += (bytes + 255) & ~(size_t)255; return p; };
  unsigned short* hbf  = (unsigned short*)alloc((size_t)MTOT * DIM * 2);
  unsigned short* WiT  = (unsigned short*)alloc((size_t)NCOL * DIM * 2);
  unsigned short* WoT  = (unsigned short*)alloc((size_t)DIM * UV * 2);
  unsigned short* u    = (unsigned short*)alloc((size_t)MTOT * UV * 2);
  unsigned short* vT   = (unsigned short*)alloc((size_t)MTOT * UV * 2);
  unsigned short* qbuf = (unsigned short*)alloc((size_t)MTOT * KEY * 2);
  unsigned short* kbuf = (unsigned short*)alloc((size_t)MTOT * KEY * 2);
  float*          ll   = (float*)alloc((size_t)MTOT * 4);
  unsigned int*   mbits= (unsigned int*)alloc((size_t)MTOT * 64 * 4);
  unsigned short* Abuf = (unsigned short*)alloc((size_t)BATCH * SEQ * SEQ * 2);
  unsigned short* g    = (unsigned short*)alloc((size_t)MTOT * UV * 2);

  k_prep<<<PREP_CVT + PREP_MASK + PREP_TWI + PREP_TWO, 256, 0, stream>>>(
      h, hbf, mask, ll, mbits, Wi, WiT, Wo, WoT);

  k_gemm1<<<dim3(MTOT / 128, NCOL / 128), 256, 0, stream>>>(
      hbf, WiT, bi, sn, cs, qg, qb, kg, kb, u, vT, qbuf, kbuf);
  k_qk<<<dim3(SEQ / 128, SEQ / 128, BATCH), 256, 0, stream>>>(qbuf, kbuf, mbits, ll, Abuf);
  k_av<<<dim3(SEQ / 128, UV / 128, BATCH), 256, 0, stream>>>(Abuf, vT, u, g);
  k_out<<<dim3(MTOT / 128, DIM / 128), 256, 0, stream>>>(g, WoT, bo, out);
}

// Round 14
// 172.972 us; speedup vs baseline: 1.1576x; 1.0445x over previous
//
#include <hip/hip_runtime.h>
#include <hip/hip_bf16.h>
#include <cstdint>

#define DIM   1024
#define KEY   128
#define UV    1024
#define NCOL  (UV*2 + KEY)   // 2176
#define SEQ   2048
#define BATCH 4
#define MTOT  (BATCH*SEQ)    // 8192
#define SCALE 0.08838834764831845f  // 1/sqrt(128)

typedef __attribute__((ext_vector_type(8))) short short8;
typedef __attribute__((ext_vector_type(4))) float f32x4;

__device__ inline unsigned short f2b(float x) {
  unsigned int u = __float_as_uint(x);
  unsigned int r = (u + 0x7fffu + ((u >> 16) & 1u)) >> 16;
  return (unsigned short)r;
}
__device__ inline float b2f(unsigned short x) {
  return __uint_as_float(((unsigned int)x) << 16);
}

__device__ inline void gload_lds16(const void* g, void* l) {
  __builtin_amdgcn_global_load_lds(
      (const __attribute__((address_space(1))) unsigned int*)g,
      (__attribute__((address_space(3))) unsigned int*)l, 16, 0, 0);
}

// ---------------------------------------------------------------------------
// 128x128 bt-GEMM tile, 4 waves (2x2), wave-tile 64x64, BK=32, double-buffered
// with counted vmcnt(4).  (round-6 core — UNCHANGED; 4 blocks/CU, conflicts 0.)
// r14 change is OUTSIDE: gemm1 split into gemm1a (1024 blocks = exactly one
// residency round, no 64-block tail) + gemm1b (KEY cols, split-K x4, 256
// blocks) + k_rfin (partial-sum + silu + gamma/beta + rope).
// ---------------------------------------------------------------------------
__device__ __forceinline__ void gemm128(
    const unsigned short* __restrict__ A, int lda,
    const unsigned short* __restrict__ Bt, int ldb,
    int K, f32x4 acc[4][4], unsigned short* lds) {
  const int tid  = threadIdx.x;
  const int lane = tid & 63;
  const int wid  = tid >> 6;      // 0..3
  const int wr   = wid >> 1, wc = wid & 1;
  const int fr   = lane & 15;
  const int fq   = lane >> 4;

#pragma unroll
  for (int i = 0; i < 4; ++i)
#pragma unroll
    for (int j = 0; j < 4; ++j) acc[i][j] = (f32x4){0.f, 0.f, 0.f, 0.f};

  auto stage = [&](int k, int d) {
    unsigned short* la = lds + d * 8192;
    unsigned short* lb = la + 4096;
#pragma unroll
    for (int p = 0; p < 2; ++p) {
      int c = p * 256 + tid;          // 0..511: r = c>>2, q = c&3
      int r = c >> 2, q = c & 3;
      int qs = q ^ ((r >> 1) & 3);    // pre-swizzled source
      gload_lds16(A + (size_t)r * lda + k * 32 + qs * 8,
                  la + (size_t)(p * 256 + wid * 64) * 8);
    }
#pragma unroll
    for (int p = 0; p < 2; ++p) {
      int c = p * 256 + tid;
      int r = c >> 2, q = c & 3;
      int qs = q ^ ((r >> 1) & 3);
      gload_lds16(Bt + (size_t)r * ldb + k * 32 + qs * 8,
                  lb + (size_t)(p * 256 + wid * 64) * 8);
    }
  };

  const int slot = (fq ^ ((fr >> 1) & 3)) * 8;
  const int rA   = (wr * 64 + fr) * 32 + slot;   // + i*512
  const int rB   = (wc * 64 + fr) * 32 + slot;   // + j*512

  const int NK = K >> 5;
  stage(0, 0);
  for (int k = 0; k < NK; ++k) {
    const int d = k & 1;
    if (k + 1 < NK) {
      stage(k + 1, d ^ 1);
      asm volatile("s_waitcnt vmcnt(4)" ::: "memory");  // stage(k) landed;
                                                        // stage(k+1) in flight
    } else {
      asm volatile("s_waitcnt vmcnt(0)" ::: "memory");
    }
    __builtin_amdgcn_s_barrier();
    asm volatile("" ::: "memory");
    const unsigned short* la = lds + d * 8192;
    const unsigned short* lb = la + 4096;
    short8 af[4], bf[4];
#pragma unroll
    for (int s = 0; s < 4; ++s) {
      af[s] = *(const short8*)&la[rA + s * 512];
      bf[s] = *(const short8*)&lb[rB + s * 512];
    }
#pragma unroll
    for (int i = 0; i < 4; ++i)
#pragma unroll
      for (int j = 0; j < 4; ++j)
        acc[i][j] = __builtin_amdgcn_mfma_f32_16x16x32_bf16(af[i], bf[j], acc[i][j], 0, 0, 0);
    asm volatile("" ::: "memory");
    __builtin_amdgcn_s_barrier();   // reads of buf d done; next iter may overwrite
    asm volatile("" ::: "memory");
  }
  // After the closing barrier, every wave's LDS reads are complete -> LDS
  // reusable by epilogue.
}

// C/D mapping: row = wr*64 + i*16 + fq*4 + r ; col = wc*64 + j*16 + fr
#define EPILOGUE_COORDS()                      \
  const int lane = threadIdx.x & 63;           \
  const int wid  = threadIdx.x >> 6;           \
  const int wr   = wid >> 1, wc = wid & 1;     \
  const int fr   = lane & 15;                  \
  const int fq   = lane >> 4;

// XCD-aware swizzle over a 2D grid (k_gemm1a only — measured win there)
__device__ __forceinline__ void xcd_swz(int& tx, int& ty) {
  const int gx = gridDim.x, gy = gridDim.y;
  const int n = gx * gy;
  const int D = blockIdx.y * gx + blockIdx.x;
  const int c = (D & 7) * (n >> 3) + (D >> 3);
  tx = c / gy;
  ty = c - tx * gy;
}

// ---------------------------------------------------------------------------
// k_prep: merged {h->bf16 cvt | mask rowsum+bitpack | Wi^T cvt | Wo^T cvt}
// ---------------------------------------------------------------------------
#define PREP_CVT   8192
#define PREP_MASK  2048
#define PREP_TWI   2176   // (NCOL/32) x (DIM/32) = 68 x 32
#define PREP_TWO   1024   // (UV/32)  x (DIM/32) = 32 x 32

__global__ __launch_bounds__(256) void k_prep(
    const float* __restrict__ h, unsigned short* __restrict__ hbf,
    const int* __restrict__ mask, float* __restrict__ ll, unsigned int* __restrict__ mb,
    const float* __restrict__ Wi, unsigned short* __restrict__ WiT,
    const float* __restrict__ Wo, unsigned short* __restrict__ WoT) {
  __shared__ float t[32][33];
  const int bid = blockIdx.x;
  const int tid = threadIdx.x;

  if (bid < PREP_CVT) {
    int id = bid * 256 + tid;
    float4 f = ((const float4*)h)[id];
    ushort4 o;
    o.x = f2b(f.x); o.y = f2b(f.y); o.z = f2b(f.z); o.w = f2b(f.w);
    ((ushort4*)hbf)[id] = o;
  } else if (bid < PREP_CVT + PREP_MASK) {
    int wid = tid >> 6, lane = tid & 63;
    int row = (bid - PREP_CVT) * 4 + wid;
    const int4* p = (const int4*)(mask + (size_t)row * SEQ);
    int s = 0;
#pragma unroll
    for (int i = 0; i < 8; ++i) {
      int4 v = p[i * 64 + lane];
      unsigned nib = (v.x != 0 ? 1u : 0u) | (v.y != 0 ? 2u : 0u) |
                     (v.z != 0 ? 4u : 0u) | (v.w != 0 ? 8u : 0u);
      unsigned w = 0;
#pragma unroll
      for (int k2 = 0; k2 < 8; ++k2)
        w |= __shfl(nib, (lane & ~7) + k2, 64) << (4 * k2);
      if ((lane & 7) == 0) mb[(size_t)row * 64 + i * 8 + (lane >> 3)] = w;
      s += v.x + v.y + v.z + v.w;
    }
    for (int off = 32; off; off >>= 1) s += __shfl_down(s, off);
    if (lane == 0) ll[row] = (float)s;
  } else {
    const float* in; unsigned short* outp; int R, C, bx, by;
    if (bid < PREP_CVT + PREP_MASK + PREP_TWI) {
      int b = bid - (PREP_CVT + PREP_MASK);
      in = Wi; outp = WiT; R = DIM; C = NCOL; bx = b % 68; by = b / 68;
    } else {
      int b = bid - (PREP_CVT + PREP_MASK + PREP_TWI);
      in = Wo; outp = WoT; R = DIM; C = UV; bx = b & 31; by = b >> 5;
    }
    int c0 = bx * 32, r0 = by * 32;
    int tx = tid & 31, ty = tid >> 5;   // 32 x 8
#pragma unroll
    for (int i = 0; i < 4; ++i)
      t[ty + i * 8][tx] = in[(size_t)(r0 + ty + i * 8) * C + c0 + tx];
    __syncthreads();
#pragma unroll
    for (int i = 0; i < 4; ++i)
      outp[(size_t)(c0 + ty + i * 8) * R + r0 + tx] = f2b(t[tx][ty + i * 8]);
  }
}

// ---------------------------------------------------------------------------
// gemm1a: u,v columns only.  grid (64, 16) = 1024 blocks = exactly one
// residency round at 4 blocks/CU (no tail).
// ---------------------------------------------------------------------------
__global__ __launch_bounds__(256, 4) void k_gemm1a(const unsigned short* __restrict__ hbf,
                                                   const unsigned short* __restrict__ WiT,
                                                   const float* __restrict__ bi,
                                                   unsigned short* __restrict__ u,
                                                   unsigned short* __restrict__ vT) {
  // 34 KiB: first 16384 shorts = GEMM double-buffer; whole array reused as
  // [128][136] transpose pad after the GEMM's closing barrier.
  __shared__ unsigned short lds[17408];
  int tx, ty; xcd_swz(tx, ty);
  int m0 = tx * 128, n0 = ty * 128;
  f32x4 acc[4][4];
  gemm128(hbf + (size_t)m0 * DIM, DIM, WiT + (size_t)n0 * DIM, DIM, DIM, acc, lds);
  EPILOGUE_COORDS();
  if (n0 < UV) {
    // u columns: silu + pack
#pragma unroll
    for (int i = 0; i < 4; ++i)
#pragma unroll
      for (int j = 0; j < 4; ++j)
#pragma unroll
        for (int r = 0; r < 4; ++r) {
          int row = m0 + wr * 64 + i * 16 + fq * 4 + r;
          int col = n0 + wc * 64 + j * 16 + fr;
          float x = acc[i][j][r] + bi[col];
          float s = x / (1.f + __expf(-x));
          u[(size_t)row * UV + col] = f2b(s);
        }
  } else {
    // v columns: silu + in-block transpose -> write vT[b][d][n] directly
    unsigned short (*t)[136] = (unsigned short (*)[136])lds;
#pragma unroll
    for (int i = 0; i < 4; ++i)
#pragma unroll
      for (int j = 0; j < 4; ++j)
#pragma unroll
        for (int r = 0; r < 4; r += 2) {
          int rl = wr * 64 + i * 16 + fq * 4 + r;     // local row (even)
          int dl = wc * 64 + j * 16 + fr;             // local v-col
          int col = n0 + dl;
          float x0 = acc[i][j][r]     + bi[col];
          float x1 = acc[i][j][r + 1] + bi[col];
          float s0 = x0 / (1.f + __expf(-x0));
          float s1 = x1 / (1.f + __expf(-x1));
          unsigned pk = (unsigned)f2b(s0) | ((unsigned)f2b(s1) << 16);
          *(unsigned*)&t[dl][rl] = pk;
        }
    __syncthreads();
    int bb = m0 >> 11;            // batch  (SEQ = 2048)
    int ns = m0 & (SEQ - 1);      // seq base
    int d0 = n0 - UV;
    const int tid = threadIdx.x;
#pragma unroll
    for (int it = 0; it < 8; ++it) {
      int idx = it * 256 + tid;   // 0..2047
      int dl = idx >> 4, q = idx & 15;
      *(int4*)&vT[((size_t)bb * UV + d0 + dl) * SEQ + ns + q * 8] =
          *(const int4*)&t[dl][q * 8];
    }
  }
}

// ---------------------------------------------------------------------------
// gemm1b: KEY columns (N=128, K=1024), split-K x4.  grid (64, 4) = 256 blocks,
// each computes a K=256 slice -> f32 partials qkp[slice][8192][128].
// ---------------------------------------------------------------------------
__global__ __launch_bounds__(256, 4) void k_gemm1b(const unsigned short* __restrict__ hbf,
                                                   const unsigned short* __restrict__ WiT,
                                                   float* __restrict__ qkp) {
  __shared__ unsigned short lds[16384];
  int m0 = blockIdx.x * 128;
  int sl = blockIdx.y;              // K-slice 0..3
  f32x4 acc[4][4];
  gemm128(hbf + (size_t)m0 * DIM + sl * 256, DIM,
          WiT + (size_t)(2 * UV) * DIM + sl * 256, DIM, 256, acc, lds);
  EPILOGUE_COORDS();
  float* dst = qkp + (size_t)sl * MTOT * KEY;
#pragma unroll
  for (int i = 0; i < 4; ++i)
#pragma unroll
    for (int j = 0; j < 4; ++j)
#pragma unroll
      for (int r = 0; r < 4; ++r) {
        int row = m0 + wr * 64 + i * 16 + fq * 4 + r;
        int col = wc * 64 + j * 16 + fr;
        dst[(size_t)row * KEY + col] = acc[i][j][r];
      }
}

// ---------------------------------------------------------------------------
// k_rfin: qk = sum of 4 partials + bias -> silu -> gamma/beta -> rope -> bf16
// ---------------------------------------------------------------------------
__global__ __launch_bounds__(256) void k_rfin(const float* __restrict__ qkp,
                                              const float* __restrict__ bi,
                                              const float* __restrict__ sn,
                                              const float* __restrict__ cs,
                                              const float* __restrict__ qg,
                                              const float* __restrict__ qb,
                                              const float* __restrict__ kg,
                                              const float* __restrict__ kb,
                                              unsigned short* __restrict__ q,
                                              unsigned short* __restrict__ k) {
  int id = blockIdx.x * 256 + threadIdx.x;  // over 8192*64
  int m = id >> 6, t = id & 63;
  int n = m & (SEQ - 1);
  const float2* p = (const float2*)qkp;     // [4][MTOT][64] float2
  float2 s0 = p[(size_t)0 * MTOT * 64 + m * 64 + t];
  float2 s1 = p[(size_t)1 * MTOT * 64 + m * 64 + t];
  float2 s2 = p[(size_t)2 * MTOT * 64 + m * 64 + t];
  float2 s3 = p[(size_t)3 * MTOT * 64 + m * 64 + t];
  float x1 = s0.x + s1.x + s2.x + s3.x + bi[2 * UV + 2 * t];
  float x2 = s0.y + s1.y + s2.y + s3.y + bi[2 * UV + 2 * t + 1];
  float sa = x1 / (1.f + __expf(-x1));
  float sb = x2 / (1.f + __expf(-x2));
  float s_ = sn[n * 64 + t], c_ = cs[n * 64 + t];
  float a1 = sa * qg[2 * t] + qb[2 * t];
  float a2 = sb * qg[2 * t + 1] + qb[2 * t + 1];
  q[m * KEY + t]      = f2b(a1 * c_ - a2 * s_);
  q[m * KEY + 64 + t] = f2b(a1 * s_ + a2 * c_);
  float b1 = sa * kg[2 * t] + kb[2 * t];
  float b2 = sb * kg[2 * t + 1] + kb[2 * t + 1];
  k[m * KEY + t]      = f2b(b1 * c_ - b2 * s_);
  k[m * KEY + 64 + t] = f2b(b1 * s_ + b2 * c_);
}

// ---------------------------------------------------------------------------
// attention-side GEMMs (natural block order — r13 measured)
// ---------------------------------------------------------------------------
__global__ __launch_bounds__(256, 4) void k_qk(const unsigned short* __restrict__ q,
                                               const unsigned short* __restrict__ k,
                                               const unsigned int* __restrict__ mb,
                                               const float* __restrict__ ll,
                                               unsigned short* __restrict__ Abuf) {
  __shared__ unsigned short lds[16384];
  int b = blockIdx.z;
  int m0 = blockIdx.x * 128, n0 = blockIdx.y * 128;
  f32x4 acc[4][4];
  gemm128(q + ((size_t)b * SEQ + m0) * KEY, KEY,
          k + ((size_t)b * SEQ + n0) * KEY, KEY, KEY, acc, lds);
  EPILOGUE_COORDS();
#pragma unroll
  for (int i = 0; i < 4; ++i)
#pragma unroll
    for (int r = 0; r < 4; ++r) {
      int row = m0 + wr * 64 + i * 16 + fq * 4 + r;
      size_t rb = (size_t)b * SEQ + row;
      unsigned long long mw =
          *(const unsigned long long*)&mb[rb * 64 + (n0 >> 5) + wc * 2];
      float rll = 1.0f / ll[rb];
#pragma unroll
      for (int j = 0; j < 4; ++j) {
        int col = n0 + wc * 64 + j * 16 + fr;
        float a = acc[i][j][r] * SCALE;
        bool on = (mw >> (j * 16 + fr)) & 1ull;
        float rel = (on && a > 0.f) ? a : 0.f;
        Abuf[rb * SEQ + col] = f2b(rel * rel * rll);
      }
    }
}

__global__ __launch_bounds__(256, 4) void k_av(const unsigned short* __restrict__ Abuf,
                                               const unsigned short* __restrict__ vT,
                                               const unsigned short* __restrict__ u,
                                               unsigned short* __restrict__ g) {
  __shared__ unsigned short lds[16384];
  int b = blockIdx.z;
  int m0 = blockIdx.x * 128, n0 = blockIdx.y * 128;
  f32x4 acc[4][4];
  gemm128(Abuf + ((size_t)b * SEQ + m0) * SEQ, SEQ,
          vT + ((size_t)b * UV + n0) * SEQ, SEQ, SEQ, acc, lds);
  EPILOGUE_COORDS();
#pragma unroll
  for (int i = 0; i < 4; ++i)
#pragma unroll
    for (int j = 0; j < 4; ++j)
#pragma unroll
      for (int r = 0; r < 4; ++r) {
        int row = m0 + wr * 64 + i * 16 + fq * 4 + r;
        int col = n0 + wc * 64 + j * 16 + fr;
        size_t gi = ((size_t)b * SEQ + row) * UV + col;
        g[gi] = f2b(acc[i][j][r] * b2f(u[gi]));
      }
}

__global__ __launch_bounds__(256, 4) void k_out(const unsigned short* __restrict__ g,
                                                const unsigned short* __restrict__ WoT,
                                                const float* __restrict__ bo,
                                                float* __restrict__ out) {
  __shared__ unsigned short lds[16384];
  int m0 = blockIdx.x * 128, n0 = blockIdx.y * 128;
  f32x4 acc[4][4];
  gemm128(g + (size_t)m0 * UV, UV, WoT + (size_t)n0 * UV, UV, UV, acc, lds);
  EPILOGUE_COORDS();
#pragma unroll
  for (int i = 0; i < 4; ++i)
#pragma unroll
    for (int j = 0; j < 4; ++j)
#pragma unroll
      for (int r = 0; r < 4; ++r) {
        int row = m0 + wr * 64 + i * 16 + fq * 4 + r;
        int col = n0 + wc * 64 + j * 16 + fr;
        out[(size_t)row * DIM + col] = acc[i][j][r] + bo[col];
      }
}

// ---------------------------------------------------------------------------
extern "C" void kernel_launch(void* const* d_in, const int* in_sizes, int n_in,
                              void* d_out, int out_size, void* d_ws, size_t ws_size,
                              hipStream_t stream) {
  const float* h    = (const float*)d_in[0];
  const int*   mask = (const int*)d_in[1];
  const float* sn   = (const float*)d_in[2];
  const float* cs   = (const float*)d_in[3];
  const float* Wi   = (const float*)d_in[4];
  const float* bi   = (const float*)d_in[5];
  const float* Wo   = (const float*)d_in[6];
  const float* bo   = (const float*)d_in[7];
  const float* qg   = (const float*)d_in[8];
  const float* qb   = (const float*)d_in[9];
  const float* kg   = (const float*)d_in[10];
  const float* kb   = (const float*)d_in[11];
  float* out = (float*)d_out;

  char* ws = (char*)d_ws;
  size_t off = 0;
  auto alloc = [&](size_t bytes) { void* p = ws + off; off += (bytes + 255) & ~(size_t)255; return p; };
  unsigned short* hbf  = (unsigned short*)alloc((size_t)MTOT * DIM * 2);
  unsigned short* WiT  = (unsigned short*)alloc((size_t)NCOL * DIM * 2);
  unsigned short* WoT  = (unsigned short*)alloc((size_t)DIM * UV * 2);
  unsigned short* u    = (unsigned short*)alloc((size_t)MTOT * UV * 2);
  unsigned short* vT   = (unsigned short*)alloc((size_t)MTOT * UV * 2);
  unsigned short* qbuf = (unsigned short*)alloc((size_t)MTOT * KEY * 2);
  unsigned short* kbuf = (unsigned short*)alloc((size_t)MTOT * KEY * 2);
  float*          qkp  = (float*)alloc((size_t)4 * MTOT * KEY * 4);
  float*          ll   = (float*)alloc((size_t)MTOT * 4);
  unsigned int*   mbits= (unsigned int*)alloc((size_t)MTOT * 64 * 4);
  unsigned short* Abuf = (unsigned short*)alloc((size_t)BATCH * SEQ * SEQ * 2);
  unsigned short* g    = (unsigned short*)alloc((size_t)MTOT * UV * 2);

  k_prep<<<PREP_CVT + PREP_MASK + PREP_TWI + PREP_TWO, 256, 0, stream>>>(
      h, hbf, mask, ll, mbits, Wi, WiT, Wo, WoT);

  k_gemm1b<<<dim3(MTOT / 128, 4), 256, 0, stream>>>(hbf, WiT, qkp);
  k_gemm1a<<<dim3(MTOT / 128, 16), 256, 0, stream>>>(hbf, WiT, bi, u, vT);
  k_rfin<<<(MTOT * 64) / 256, 256, 0, stream>>>(qkp, bi, sn, cs, qg, qb, kg, kb, qbuf, kbuf);
  k_qk<<<dim3(SEQ / 128, SEQ / 128, BATCH), 256, 0, stream>>>(qbuf, kbuf, mbits, ll, Abuf);
  k_av<<<dim3(SEQ / 128, UV / 128, BATCH), 256, 0, stream>>>(Abuf, vT, u, g);
  k_out<<<dim3(MTOT / 128, DIM / 128), 256, 0, stream>>>(g, WoT, bo, out);
}

// Round 16
// 172.354 us; speedup vs baseline: 1.1618x; 1.0036x over previous
//
#include <hip/hip_runtime.h>
#include <hip/hip_bf16.h>
#include <cstdint>

#define DIM   1024
#define KEY   128
#define UV    1024
#define NCOL  (UV*2 + KEY)   // 2176
#define SEQ   2048
#define BATCH 4
#define MTOT  (BATCH*SEQ)    // 8192
#define SCALE 0.08838834764831845f  // 1/sqrt(128)

typedef __attribute__((ext_vector_type(8))) short short8;
typedef __attribute__((ext_vector_type(4))) float f32x4;

__device__ inline unsigned short f2b(float x) {
  unsigned int u = __float_as_uint(x);
  unsigned int r = (u + 0x7fffu + ((u >> 16) & 1u)) >> 16;
  return (unsigned short)r;
}
__device__ inline float b2f(unsigned short x) {
  return __uint_as_float(((unsigned int)x) << 16);
}

__device__ inline void gload_lds16(const void* g, void* l) {
  __builtin_amdgcn_global_load_lds(
      (const __attribute__((address_space(1))) unsigned int*)g,
      (__attribute__((address_space(3))) unsigned int*)l, 16, 0, 0);
}

// ---------------------------------------------------------------------------
// 128x128 bt-GEMM tile, 4 waves (2x2), wave-tile 64x64, BK=32, double-buffered
// with counted vmcnt(4).  (round-6 core; 4 blocks/CU, LDS conflicts 0.)
// Structure = r14 exactly (best measured, 173.0 µs): gemm1 split into
// gemm1a (1024 blocks = one residency round, no tail) + gemm1b (KEY cols,
// split-K x4) + k_rfin.  r15's mega-merge failed replay re-validation and
// is abandoned.
// ---------------------------------------------------------------------------
__device__ __forceinline__ void gemm128(
    const unsigned short* __restrict__ A, int lda,
    const unsigned short* __restrict__ Bt, int ldb,
    int K, f32x4 acc[4][4], unsigned short* lds) {
  const int tid  = threadIdx.x;
  const int lane = tid & 63;
  const int wid  = tid >> 6;      // 0..3
  const int wr   = wid >> 1, wc = wid & 1;
  const int fr   = lane & 15;
  const int fq   = lane >> 4;

#pragma unroll
  for (int i = 0; i < 4; ++i)
#pragma unroll
    for (int j = 0; j < 4; ++j) acc[i][j] = (f32x4){0.f, 0.f, 0.f, 0.f};

  auto stage = [&](int k, int d) {
    unsigned short* la = lds + d * 8192;
    unsigned short* lb = la + 4096;
#pragma unroll
    for (int p = 0; p < 2; ++p) {
      int c = p * 256 + tid;          // 0..511: r = c>>2, q = c&3
      int r = c >> 2, q = c & 3;
      int qs = q ^ ((r >> 1) & 3);    // pre-swizzled source
      gload_lds16(A + (size_t)r * lda + k * 32 + qs * 8,
                  la + (size_t)(p * 256 + wid * 64) * 8);
    }
#pragma unroll
    for (int p = 0; p < 2; ++p) {
      int c = p * 256 + tid;
      int r = c >> 2, q = c & 3;
      int qs = q ^ ((r >> 1) & 3);
      gload_lds16(Bt + (size_t)r * ldb + k * 32 + qs * 8,
                  lb + (size_t)(p * 256 + wid * 64) * 8);
    }
  };

  const int slot = (fq ^ ((fr >> 1) & 3)) * 8;
  const int rA   = (wr * 64 + fr) * 32 + slot;   // + i*512
  const int rB   = (wc * 64 + fr) * 32 + slot;   // + j*512

  const int NK = K >> 5;
  stage(0, 0);
  for (int k = 0; k < NK; ++k) {
    const int d = k & 1;
    if (k + 1 < NK) {
      stage(k + 1, d ^ 1);
      asm volatile("s_waitcnt vmcnt(4)" ::: "memory");  // stage(k) landed;
                                                        // stage(k+1) in flight
    } else {
      asm volatile("s_waitcnt vmcnt(0)" ::: "memory");
    }
    __builtin_amdgcn_s_barrier();
    asm volatile("" ::: "memory");
    const unsigned short* la = lds + d * 8192;
    const unsigned short* lb = la + 4096;
    short8 af[4], bf[4];
#pragma unroll
    for (int s = 0; s < 4; ++s) {
      af[s] = *(const short8*)&la[rA + s * 512];
      bf[s] = *(const short8*)&lb[rB + s * 512];
    }
#pragma unroll
    for (int i = 0; i < 4; ++i)
#pragma unroll
      for (int j = 0; j < 4; ++j)
        acc[i][j] = __builtin_amdgcn_mfma_f32_16x16x32_bf16(af[i], bf[j], acc[i][j], 0, 0, 0);
    asm volatile("" ::: "memory");
    __builtin_amdgcn_s_barrier();   // reads of buf d done; next iter may overwrite
    asm volatile("" ::: "memory");
  }
  // After the closing barrier, every wave's LDS reads are complete -> LDS
  // reusable by epilogue.
}

// C/D mapping: row = wr*64 + i*16 + fq*4 + r ; col = wc*64 + j*16 + fr
#define EPILOGUE_COORDS()                      \
  const int lane = threadIdx.x & 63;           \
  const int wid  = threadIdx.x >> 6;           \
  const int wr   = wid >> 1, wc = wid & 1;     \
  const int fr   = lane & 15;                  \
  const int fq   = lane >> 4;

// XCD-aware swizzle over a 2D grid (k_gemm1a only — measured win there)
__device__ __forceinline__ void xcd_swz(int& tx, int& ty) {
  const int gx = gridDim.x, gy = gridDim.y;
  const int n = gx * gy;
  const int D = blockIdx.y * gx + blockIdx.x;
  const int c = (D & 7) * (n >> 3) + (D >> 3);
  tx = c / gy;
  ty = c - tx * gy;
}

// ---------------------------------------------------------------------------
// k_prep: merged {h->bf16 cvt | mask rowsum+bitpack | Wi^T cvt | Wo^T cvt}
// ---------------------------------------------------------------------------
#define PREP_CVT   8192
#define PREP_MASK  2048
#define PREP_TWI   2176   // (NCOL/32) x (DIM/32) = 68 x 32
#define PREP_TWO   1024   // (UV/32)  x (DIM/32) = 32 x 32

__global__ __launch_bounds__(256) void k_prep(
    const float* __restrict__ h, unsigned short* __restrict__ hbf,
    const int* __restrict__ mask, float* __restrict__ ll, unsigned int* __restrict__ mb,
    const float* __restrict__ Wi, unsigned short* __restrict__ WiT,
    const float* __restrict__ Wo, unsigned short* __restrict__ WoT) {
  __shared__ float t[32][33];
  const int bid = blockIdx.x;
  const int tid = threadIdx.x;

  if (bid < PREP_CVT) {
    int id = bid * 256 + tid;
    float4 f = ((const float4*)h)[id];
    ushort4 o;
    o.x = f2b(f.x); o.y = f2b(f.y); o.z = f2b(f.z); o.w = f2b(f.w);
    ((ushort4*)hbf)[id] = o;
  } else if (bid < PREP_CVT + PREP_MASK) {
    int wid = tid >> 6, lane = tid & 63;
    int row = (bid - PREP_CVT) * 4 + wid;
    const int4* p = (const int4*)(mask + (size_t)row * SEQ);
    int s = 0;
#pragma unroll
    for (int i = 0; i < 8; ++i) {
      int4 v = p[i * 64 + lane];
      unsigned nib = (v.x != 0 ? 1u : 0u) | (v.y != 0 ? 2u : 0u) |
                     (v.z != 0 ? 4u : 0u) | (v.w != 0 ? 8u : 0u);
      unsigned w = 0;
#pragma unroll
      for (int k2 = 0; k2 < 8; ++k2)
        w |= __shfl(nib, (lane & ~7) + k2, 64) << (4 * k2);
      if ((lane & 7) == 0) mb[(size_t)row * 64 + i * 8 + (lane >> 3)] = w;
      s += v.x + v.y + v.z + v.w;
    }
    for (int off = 32; off; off >>= 1) s += __shfl_down(s, off);
    if (lane == 0) ll[row] = (float)s;
  } else {
    const float* in; unsigned short* outp; int R, C, bx, by;
    if (bid < PREP_CVT + PREP_MASK + PREP_TWI) {
      int b = bid - (PREP_CVT + PREP_MASK);
      in = Wi; outp = WiT; R = DIM; C = NCOL; bx = b % 68; by = b / 68;
    } else {
      int b = bid - (PREP_CVT + PREP_MASK + PREP_TWI);
      in = Wo; outp = WoT; R = DIM; C = UV; bx = b & 31; by = b >> 5;
    }
    int c0 = bx * 32, r0 = by * 32;
    int tx = tid & 31, ty = tid >> 5;   // 32 x 8
#pragma unroll
    for (int i = 0; i < 4; ++i)
      t[ty + i * 8][tx] = in[(size_t)(r0 + ty + i * 8) * C + c0 + tx];
    __syncthreads();
#pragma unroll
    for (int i = 0; i < 4; ++i)
      outp[(size_t)(c0 + ty + i * 8) * R + r0 + tx] = f2b(t[tx][ty + i * 8]);
  }
}

// ---------------------------------------------------------------------------
// gemm1a: u,v columns only.  grid (64, 16) = 1024 blocks = exactly one
// residency round at 4 blocks/CU (no tail).
// ---------------------------------------------------------------------------
__global__ __launch_bounds__(256, 4) void k_gemm1a(const unsigned short* __restrict__ hbf,
                                                   const unsigned short* __restrict__ WiT,
                                                   const float* __restrict__ bi,
                                                   unsigned short* __restrict__ u,
                                                   unsigned short* __restrict__ vT) {
  // 34 KiB: first 16384 shorts = GEMM double-buffer; whole array reused as
  // [128][136] transpose pad after the GEMM's closing barrier.
  __shared__ unsigned short lds[17408];
  int tx, ty; xcd_swz(tx, ty);
  int m0 = tx * 128, n0 = ty * 128;
  f32x4 acc[4][4];
  gemm128(hbf + (size_t)m0 * DIM, DIM, WiT + (size_t)n0 * DIM, DIM, DIM, acc, lds);
  EPILOGUE_COORDS();
  if (n0 < UV) {
    // u columns: silu + pack
#pragma unroll
    for (int i = 0; i < 4; ++i)
#pragma unroll
      for (int j = 0; j < 4; ++j)
#pragma unroll
        for (int r = 0; r < 4; ++r) {
          int row = m0 + wr * 64 + i * 16 + fq * 4 + r;
          int col = n0 + wc * 64 + j * 16 + fr;
          float x = acc[i][j][r] + bi[col];
          float s = x / (1.f + __expf(-x));
          u[(size_t)row * UV + col] = f2b(s);
        }
  } else {
    // v columns: silu + in-block transpose -> write vT[b][d][n] directly
    unsigned short (*t)[136] = (unsigned short (*)[136])lds;
#pragma unroll
    for (int i = 0; i < 4; ++i)
#pragma unroll
      for (int j = 0; j < 4; ++j)
#pragma unroll
        for (int r = 0; r < 4; r += 2) {
          int rl = wr * 64 + i * 16 + fq * 4 + r;     // local row (even)
          int dl = wc * 64 + j * 16 + fr;             // local v-col
          int col = n0 + dl;
          float x0 = acc[i][j][r]     + bi[col];
          float x1 = acc[i][j][r + 1] + bi[col];
          float s0 = x0 / (1.f + __expf(-x0));
          float s1 = x1 / (1.f + __expf(-x1));
          unsigned pk = (unsigned)f2b(s0) | ((unsigned)f2b(s1) << 16);
          *(unsigned*)&t[dl][rl] = pk;
        }
    __syncthreads();
    int bb = m0 >> 11;            // batch  (SEQ = 2048)
    int ns = m0 & (SEQ - 1);      // seq base
    int d0 = n0 - UV;
    const int tid = threadIdx.x;
#pragma unroll
    for (int it = 0; it < 8; ++it) {
      int idx = it * 256 + tid;   // 0..2047
      int dl = idx >> 4, q = idx & 15;
      *(int4*)&vT[((size_t)bb * UV + d0 + dl) * SEQ + ns + q * 8] =
          *(const int4*)&t[dl][q * 8];
    }
  }
}

// ---------------------------------------------------------------------------
// gemm1b: KEY columns (N=128, K=1024), split-K x4.  grid (64, 4) = 256 blocks,
// each computes a K=256 slice -> f32 partials qkp[slice][8192][128].
// ---------------------------------------------------------------------------
__global__ __launch_bounds__(256, 4) void k_gemm1b(const unsigned short* __restrict__ hbf,
                                                   const unsigned short* __restrict__ WiT,
                                                   float* __restrict__ qkp) {
  __shared__ unsigned short lds[16384];
  int m0 = blockIdx.x * 128;
  int sl = blockIdx.y;              // K-slice 0..3
  f32x4 acc[4][4];
  gemm128(hbf + (size_t)m0 * DIM + sl * 256, DIM,
          WiT + (size_t)(2 * UV) * DIM + sl * 256, DIM, 256, acc, lds);
  EPILOGUE_COORDS();
  float* dst = qkp + (size_t)sl * MTOT * KEY;
#pragma unroll
  for (int i = 0; i < 4; ++i)
#pragma unroll
    for (int j = 0; j < 4; ++j)
#pragma unroll
      for (int r = 0; r < 4; ++r) {
        int row = m0 + wr * 64 + i * 16 + fq * 4 + r;
        int col = wc * 64 + j * 16 + fr;
        dst[(size_t)row * KEY + col] = acc[i][j][r];
      }
}

// ---------------------------------------------------------------------------
// k_rfin: qk = sum of 4 partials + bias -> silu -> gamma/beta -> rope -> bf16
// ---------------------------------------------------------------------------
__global__ __launch_bounds__(256) void k_rfin(const float* __restrict__ qkp,
                                              const float* __restrict__ bi,
                                              const float* __restrict__ sn,
                                              const float* __restrict__ cs,
                                              const float* __restrict__ qg,
                                              const float* __restrict__ qb,
                                              const float* __restrict__ kg,
                                              const float* __restrict__ kb,
                                              unsigned short* __restrict__ q,
                                              unsigned short* __restrict__ k) {
  int id = blockIdx.x * 256 + threadIdx.x;  // over 8192*64
  int m = id >> 6, t = id & 63;
  int n = m & (SEQ - 1);
  const float2* p = (const float2*)qkp;     // [4][MTOT][64] float2
  float2 s0 = p[(size_t)0 * MTOT * 64 + m * 64 + t];
  float2 s1 = p[(size_t)1 * MTOT * 64 + m * 64 + t];
  float2 s2 = p[(size_t)2 * MTOT * 64 + m * 64 + t];
  float2 s3 = p[(size_t)3 * MTOT * 64 + m * 64 + t];
  float x1 = s0.x + s1.x + s2.x + s3.x + bi[2 * UV + 2 * t];
  float x2 = s0.y + s1.y + s2.y + s3.y + bi[2 * UV + 2 * t + 1];
  float sa = x1 / (1.f + __expf(-x1));
  float sb = x2 / (1.f + __expf(-x2));
  float s_ = sn[n * 64 + t], c_ = cs[n * 64 + t];
  float a1 = sa * qg[2 * t] + qb[2 * t];
  float a2 = sb * qg[2 * t + 1] + qb[2 * t + 1];
  q[m * KEY + t]      = f2b(a1 * c_ - a2 * s_);
  q[m * KEY + 64 + t] = f2b(a1 * s_ + a2 * c_);
  float b1 = sa * kg[2 * t] + kb[2 * t];
  float b2 = sb * kg[2 * t + 1] + kb[2 * t + 1];
  k[m * KEY + t]      = f2b(b1 * c_ - b2 * s_);
  k[m * KEY + 64 + t] = f2b(b1 * s_ + b2 * c_);
}

// ---------------------------------------------------------------------------
// attention-side GEMMs (natural block order — r13 measured)
// ---------------------------------------------------------------------------
__global__ __launch_bounds__(256, 4) void k_qk(const unsigned short* __restrict__ q,
                                               const unsigned short* __restrict__ k,
                                               const unsigned int* __restrict__ mb,
                                               const float* __restrict__ ll,
                                               unsigned short* __restrict__ Abuf) {
  __shared__ unsigned short lds[16384];
  int b = blockIdx.z;
  int m0 = blockIdx.x * 128, n0 = blockIdx.y * 128;
  f32x4 acc[4][4];
  gemm128(q + ((size_t)b * SEQ + m0) * KEY, KEY,
          k + ((size_t)b * SEQ + n0) * KEY, KEY, KEY, acc, lds);
  EPILOGUE_COORDS();
#pragma unroll
  for (int i = 0; i < 4; ++i)
#pragma unroll
    for (int r = 0; r < 4; ++r) {
      int row = m0 + wr * 64 + i * 16 + fq * 4 + r;
      size_t rb = (size_t)b * SEQ + row;
      unsigned long long mw =
          *(const unsigned long long*)&mb[rb * 64 + (n0 >> 5) + wc * 2];
      float rll = 1.0f / ll[rb];
#pragma unroll
      for (int j = 0; j < 4; ++j) {
        int col = n0 + wc * 64 + j * 16 + fr;
        float a = acc[i][j][r] * SCALE;
        bool on = (mw >> (j * 16 + fr)) & 1ull;
        float rel = (on && a > 0.f) ? a : 0.f;
        Abuf[rb * SEQ + col] = f2b(rel * rel * rll);
      }
    }
}

__global__ __launch_bounds__(256, 4) void k_av(const unsigned short* __restrict__ Abuf,
                                               const unsigned short* __restrict__ vT,
                                               const unsigned short* __restrict__ u,
                                               unsigned short* __restrict__ g) {
  __shared__ unsigned short lds[16384];
  int b = blockIdx.z;
  int m0 = blockIdx.x * 128, n0 = blockIdx.y * 128;
  f32x4 acc[4][4];
  gemm128(Abuf + ((size_t)b * SEQ + m0) * SEQ, SEQ,
          vT + ((size_t)b * UV + n0) * SEQ, SEQ, SEQ, acc, lds);
  EPILOGUE_COORDS();
#pragma unroll
  for (int i = 0; i < 4; ++i)
#pragma unroll
    for (int j = 0; j < 4; ++j)
#pragma unroll
      for (int r = 0; r < 4; ++r) {
        int row = m0 + wr * 64 + i * 16 + fq * 4 + r;
        int col = n0 + wc * 64 + j * 16 + fr;
        size_t gi = ((size_t)b * SEQ + row) * UV + col;
        g[gi] = f2b(acc[i][j][r] * b2f(u[gi]));
      }
}

__global__ __launch_bounds__(256, 4) void k_out(const unsigned short* __restrict__ g,
                                                const unsigned short* __restrict__ WoT,
                                                const float* __restrict__ bo,
                                                float* __restrict__ out) {
  __shared__ unsigned short lds[16384];
  int m0 = blockIdx.x * 128, n0 = blockIdx.y * 128;
  f32x4 acc[4][4];
  gemm128(g + (size_t)m0 * UV, UV, WoT + (size_t)n0 * UV, UV, UV, acc, lds);
  EPILOGUE_COORDS();
#pragma unroll
  for (int i = 0; i < 4; ++i)
#pragma unroll
    for (int j = 0; j < 4; ++j)
#pragma unroll
      for (int r = 0; r < 4; ++r) {
        int row = m0 + wr * 64 + i * 16 + fq * 4 + r;
        int col = n0 + wc * 64 + j * 16 + fr;
        out[(size_t)row * DIM + col] = acc[i][j][r] + bo[col];
      }
}

// ---------------------------------------------------------------------------
extern "C" void kernel_launch(void* const* d_in, const int* in_sizes, int n_in,
                              void* d_out, int out_size, void* d_ws, size_t ws_size,
                              hipStream_t stream) {
  const float* h    = (const float*)d_in[0];
  const int*   mask = (const int*)d_in[1];
  const float* sn   = (const float*)d_in[2];
  const float* cs   = (const float*)d_in[3];
  const float* Wi   = (const float*)d_in[4];
  const float* bi   = (const float*)d_in[5];
  const float* Wo   = (const float*)d_in[6];
  const float* bo   = (const float*)d_in[7];
  const float* qg   = (const float*)d_in[8];
  const float* qb   = (const float*)d_in[9];
  const float* kg   = (const float*)d_in[10];
  const float* kb   = (const float*)d_in[11];
  float* out = (float*)d_out;

  char* ws = (char*)d_ws;
  size_t off = 0;
  auto alloc = [&](size_t bytes) { void* p = ws + off; off += (bytes + 255) & ~(size_t)255; return p; };
  unsigned short* hbf  = (unsigned short*)alloc((size_t)MTOT * DIM * 2);
  unsigned short* WiT  = (unsigned short*)alloc((size_t)NCOL * DIM * 2);
  unsigned short* WoT  = (unsigned short*)alloc((size_t)DIM * UV * 2);
  unsigned short* u    = (unsigned short*)alloc((size_t)MTOT * UV * 2);
  unsigned short* vT   = (unsigned short*)alloc((size_t)MTOT * UV * 2);
  unsigned short* qbuf = (unsigned short*)alloc((size_t)MTOT * KEY * 2);
  unsigned short* kbuf = (unsigned short*)alloc((size_t)MTOT * KEY * 2);
  float*          qkp  = (float*)alloc((size_t)4 * MTOT * KEY * 4);
  float*          ll   = (float*)alloc((size_t)MTOT * 4);
  unsigned int*   mbits= (unsigned int*)alloc((size_t)MTOT * 64 * 4);
  unsigned short* Abuf = (unsigned short*)alloc((size_t)BATCH * SEQ * SEQ * 2);
  unsigned short* g    = (unsigned short*)alloc((size_t)MTOT * UV * 2);

  k_prep<<<PREP_CVT + PREP_MASK + PREP_TWI + PREP_TWO, 256, 0, stream>>>(
      h, hbf, mask, ll, mbits, Wi, WiT, Wo, WoT);

  k_gemm1b<<<dim3(MTOT / 128, 4), 256, 0, stream>>>(hbf, WiT, qkp);
  k_gemm1a<<<dim3(MTOT / 128, 16), 256, 0, stream>>>(hbf, WiT, bi, u, vT);
  k_rfin<<<(MTOT * 64) / 256, 256, 0, stream>>>(qkp, bi, sn, cs, qg, qb, kg, kb, qbuf, kbuf);
  k_qk<<<dim3(SEQ / 128, SEQ / 128, BATCH), 256, 0, stream>>>(qbuf, kbuf, mbits, ll, Abuf);
  k_av<<<dim3(SEQ / 128, UV / 128, BATCH), 256, 0, stream>>>(Abuf, vT, u, g);
  k_out<<<dim3(MTOT / 128, DIM / 128), 256, 0, stream>>>(g, WoT, bo, out);
}